// Round 1
// baseline (15714.742 us; speedup 1.0000x reference)
//
#include <hip/hip_runtime.h>

#define EPSF 1e-5f

// ---------------------------------------------------------------------------
// Geometry: B=1, C=32, H=96, W=128, L=2, R=3, N=7 (49 displacement samples)
// ---------------------------------------------------------------------------
// Pipeline per level:
//   x0 [DC][64][96][128]  = concat(f1, grid_sample(f2, coords/2^i + delta))
//   x1 [DC][96][96][128]  = relu(bn1(conv3x3 s1 (x0)))
//   x2 [DC][128][48][64]  = relu(bn2(conv3x3 s2 (x1)))
//   x3 [DC][128][48][64]  = relu(bn3(conv3x3 s1 (x2)))
//   x4 [DC][64][48][64]   = relu(bn4(conv3x3 s1 (x3)))
//   x5 [DC][32][96][128]  = relu(bn5(convT4x4 s2 (x4)))
//   cost [49][96][128]    = conv3x3(x5 -> 1ch) + bias
//   out[l*49+p][hw]       = sum_q dap[p][q] cost[q][hw]
// ---------------------------------------------------------------------------

// ------------------------- weight repack kernels ---------------------------
// OIHW [COUT][CIN][3][3] -> [CIN*9][COUT]
__global__ __launch_bounds__(256) void k_repack_oihw(
    const float* __restrict__ src, float* __restrict__ dst, int COUT, int CIN)
{
    int idx = blockIdx.x * 256 + threadIdx.x;
    int total = COUT * CIN * 9;
    if (idx >= total) return;
    int co = idx / (CIN * 9);
    int rem = idx % (CIN * 9);
    dst[rem * COUT + co] = src[idx];
}

// ctw5 [64][32][4][4] -> [64*16][32]
__global__ __launch_bounds__(256) void k_repack_ctw(
    const float* __restrict__ src, float* __restrict__ dst)
{
    int idx = blockIdx.x * 256 + threadIdx.x;
    if (idx >= 64 * 32 * 16) return;
    int ci = idx >> 9;
    int rem = idx & 511;
    int co = rem >> 4;
    int t  = rem & 15;
    dst[(ci * 16 + t) * 32 + co] = src[idx];
}

// ------------------------- sample + concat ---------------------------------
__global__ __launch_bounds__(256) void k_sample_concat(
    const float* __restrict__ f1, const float* __restrict__ f2,
    const float* __restrict__ coords, float* __restrict__ x0,
    int d0, float inv_scale)
{
    const int HW = 96 * 128;
    int sp = blockIdx.x * 256 + threadIdx.x;   // 0..12287
    int dd = blockIdx.z;
    int d  = d0 + dd;
    int du = d / 7, dv = d % 7;

    float cx = coords[sp] * inv_scale + (float)(du - 3);
    float cy = coords[HW + sp] * inv_scale + (float)(dv - 3);

    float xf = floorf(cx), yf = floorf(cy);
    float wx = cx - xf,    wy = cy - yf;
    int xi = (int)xf, yi = (int)yf;
    float vx0 = (xf >= 0.f        && xf <= 127.f)        ? 1.f : 0.f;
    float vx1 = (xf + 1.f >= 0.f  && xf + 1.f <= 127.f)  ? 1.f : 0.f;
    float vy0 = (yf >= 0.f        && yf <= 95.f)         ? 1.f : 0.f;
    float vy1 = (yf + 1.f >= 0.f  && yf + 1.f <= 95.f)   ? 1.f : 0.f;
    int x0i = min(max(xi, 0), 127);
    int x1i = min(max(xi + 1, 0), 127);
    int y0i = min(max(yi, 0), 95);
    int y1i = min(max(yi + 1, 0), 95);
    float w00 = (1.f - wx) * (1.f - wy) * vx0 * vy0;
    float w01 = wx * (1.f - wy) * vx1 * vy0;
    float w10 = (1.f - wx) * wy * vx0 * vy1;
    float w11 = wx * wy * vx1 * vy1;
    int o00 = y0i * 128 + x0i, o01 = y0i * 128 + x1i;
    int o10 = y1i * 128 + x0i, o11 = y1i * 128 + x1i;

    float* ob = x0 + (size_t)dd * 64 * HW + sp;
    #pragma unroll 4
    for (int c = 0; c < 32; ++c)
        ob[c * HW] = f1[c * HW + sp];
    float* o2 = ob + 32 * HW;
    #pragma unroll 4
    for (int c = 0; c < 32; ++c) {
        const float* fc = f2 + c * HW;
        o2[c * HW] = w00 * fc[o00] + w01 * fc[o01] + w10 * fc[o10] + w11 * fc[o11];
    }
}

// ------------------------- direct conv3x3 + BN + ReLU ----------------------
// wrep layout: [CIN*9][COUT].  Each thread: one spatial pos, 16 out channels.
template <int CIN, int COUT, int STRIDE, int IH, int IW, int OH, int OW>
__global__ __launch_bounds__(256) void k_conv3x3_bn_relu(
    const float* __restrict__ in, float* __restrict__ out,
    const float* __restrict__ wrep,
    const float* __restrict__ bs, const float* __restrict__ bb,
    const float* __restrict__ bm, const float* __restrict__ bv)
{
    const int sp = blockIdx.x * 256 + threadIdx.x;  // 0..OH*OW-1
    const int oh = sp / OW, ow = sp % OW;
    const int co0 = blockIdx.y * 16;
    const int dd = blockIdx.z;
    const float* ib = in + (size_t)dd * CIN * IH * IW;

    float acc[16];
    #pragma unroll
    for (int j = 0; j < 16; ++j) acc[j] = 0.f;

    const int ih0 = oh * STRIDE - 1, iw0 = ow * STRIDE - 1;
    #pragma unroll 1
    for (int ci = 0; ci < CIN; ++ci) {
        const float* ip = ib + (size_t)ci * IH * IW;
        const float* wp = wrep + (size_t)(ci * 9) * COUT + co0;
        #pragma unroll
        for (int kh = 0; kh < 3; ++kh) {
            const int ih = ih0 + kh;
            if (ih < 0 || ih >= IH) continue;
            #pragma unroll
            for (int kw = 0; kw < 3; ++kw) {
                const int iw = iw0 + kw;
                if (iw < 0 || iw >= IW) continue;
                const float v = ip[ih * IW + iw];
                const float* wq = wp + (kh * 3 + kw) * COUT;
                #pragma unroll
                for (int j = 0; j < 16; ++j)
                    acc[j] = fmaf(v, wq[j], acc[j]);
            }
        }
    }

    float* ob = out + ((size_t)dd * COUT + co0) * (OH * OW) + sp;
    #pragma unroll
    for (int j = 0; j < 16; ++j) {
        const int ch = co0 + j;
        const float inv = bs[ch] * rsqrtf(bv[ch] + EPSF);
        const float y = acc[j] * inv + (bb[ch] - bm[ch] * inv);
        ob[j * (OH * OW)] = fmaxf(y, 0.f);
    }
}

// ------------------------- convT 4x4 s2 + BN + ReLU ------------------------
// in [DC][64][48][64] -> out [DC][32][96][128].  wrep5: [64*16][32].
// blockIdx.y = ct*4 + ph*2 + pw  (ct: co tile of 16; ph/pw: output parity)
__global__ __launch_bounds__(256) void k_convt_bn_relu(
    const float* __restrict__ in, float* __restrict__ out,
    const float* __restrict__ wrep,
    const float* __restrict__ bs, const float* __restrict__ bb,
    const float* __restrict__ bm, const float* __restrict__ bv)
{
    const int t = blockIdx.x * 256 + threadIdx.x;   // 0..3071
    const int q = t / 64, r = t % 64;               // 48 x 64 parity grid
    const int ct = blockIdx.y >> 2;
    const int ph = (blockIdx.y >> 1) & 1, pw = blockIdx.y & 1;
    const int co0 = ct * 16;
    const int dd = blockIdx.z;
    const int oh = 2 * q + ph, ow = 2 * r + pw;
    const int kh0 = (oh + 1) & 1, kw0 = (ow + 1) & 1;   // uniform per block
    const int ihA = (oh + 1 - kh0) >> 1;  // tap kh0   (kh0+2 -> ihA-1)
    const int iwA = (ow + 1 - kw0) >> 1;
    const bool vhA = ihA < 48, vhB = ihA >= 1;
    const bool vwA = iwA < 64, vwB = iwA >= 1;

    float acc[16];
    #pragma unroll
    for (int j = 0; j < 16; ++j) acc[j] = 0.f;

    #pragma unroll 1
    for (int ci = 0; ci < 64; ++ci) {
        const float* ip = in + ((size_t)dd * 64 + ci) * (48 * 64);
        const float* wp = wrep + (size_t)(ci * 16) * 32 + co0;
        #pragma unroll
        for (int a = 0; a < 2; ++a) {
            const int kh = kh0 + 2 * a;
            const int ih = ihA - a;
            if (!(a ? vhB : vhA)) continue;
            #pragma unroll
            for (int b2 = 0; b2 < 2; ++b2) {
                const int kw = kw0 + 2 * b2;
                const int iw = iwA - b2;
                if (!(b2 ? vwB : vwA)) continue;
                const float v = ip[ih * 64 + iw];
                const float* wq = wp + (kh * 4 + kw) * 32;
                #pragma unroll
                for (int j = 0; j < 16; ++j)
                    acc[j] = fmaf(v, wq[j], acc[j]);
            }
        }
    }

    float* ob = out + ((size_t)dd * 32 + co0) * (96 * 128) + oh * 128 + ow;
    #pragma unroll
    for (int j = 0; j < 16; ++j) {
        const int ch = co0 + j;
        const float inv = bs[ch] * rsqrtf(bv[ch] + EPSF);
        const float y = acc[j] * inv + (bb[ch] - bm[ch] * inv);
        ob[j * (96 * 128)] = fmaxf(y, 0.f);
    }
}

// ------------------------- conv6 (32->1) + bias ----------------------------
__global__ __launch_bounds__(256) void k_conv6_bias(
    const float* __restrict__ in,     // [DC][32][96][128]
    float* __restrict__ cost,         // [49][96*128]
    const float* __restrict__ w,      // [32][3][3]
    const float* __restrict__ biasp,  // cb6 + level
    int d0)
{
    const int sp = blockIdx.x * 256 + threadIdx.x;
    const int dd = blockIdx.z;
    const int oh = sp / 128, ow = sp % 128;
    float acc = 0.f;
    #pragma unroll 1
    for (int ci = 0; ci < 32; ++ci) {
        const float* ip = in + ((size_t)dd * 32 + ci) * (96 * 128);
        const float* wp = w + ci * 9;
        #pragma unroll
        for (int kh = 0; kh < 3; ++kh) {
            const int ih = oh - 1 + kh;
            if (ih < 0 || ih >= 96) continue;
            #pragma unroll
            for (int kw = 0; kw < 3; ++kw) {
                const int iw = ow - 1 + kw;
                if (iw < 0 || iw >= 128) continue;
                acc = fmaf(ip[ih * 128 + iw], wp[kh * 3 + kw], acc);
            }
        }
    }
    cost[(size_t)(d0 + dd) * (96 * 128) + sp] = acc + biasp[0];
}

// ------------------------- DAP (49x49 over channels) -----------------------
__global__ __launch_bounds__(256) void k_dap(
    const float* __restrict__ cost,   // [49][12288]
    const float* __restrict__ dw,     // [49][49] (level offset applied)
    float* __restrict__ out)          // [49][12288] (level offset applied)
{
    const int sp = blockIdx.x * 256 + threadIdx.x;
    const int p = blockIdx.y;
    const float* dr = dw + p * 49;
    float acc = 0.f;
    #pragma unroll
    for (int qq = 0; qq < 49; ++qq)
        acc = fmaf(dr[qq], cost[qq * 12288 + sp], acc);
    out[(size_t)p * 12288 + sp] = acc;
}

// ---------------------------------------------------------------------------
extern "C" void kernel_launch(void* const* d_in, const int* in_sizes, int n_in,
                              void* d_out, int out_size, void* d_ws, size_t ws_size,
                              hipStream_t stream)
{
    const float* fm1[2] = { (const float*)d_in[0], (const float*)d_in[2] };
    const float* fm2[2] = { (const float*)d_in[1], (const float*)d_in[3] };
    const float* coords = (const float*)d_in[4];
    const float* cw1  = (const float*)d_in[5];
    const float* cw2  = (const float*)d_in[6];
    const float* cw3  = (const float*)d_in[7];
    const float* cw4  = (const float*)d_in[8];
    const float* ctw5 = (const float*)d_in[9];
    const float* cw6  = (const float*)d_in[10];
    const float* cb6  = (const float*)d_in[11];
    const float* bn[5][4];
    for (int j = 0; j < 5; ++j)
        for (int k = 0; k < 4; ++k)
            bn[j][k] = (const float*)d_in[12 + j * 4 + k];
    const float* dap = (const float*)d_in[32];
    float* out = (float*)d_out;

    // workspace requirement in floats for chunk size DC
    auto needF = [](long DC) -> size_t {
        return (size_t)DC * 12288 * (64 + 96 + 32)
             + (size_t)DC * 3072 * (128 + 128 + 64)
             + (size_t)49 * 12288
             + 2 * (size_t)(96*64*9 + 128*96*9 + 128*128*9 + 64*128*9 + 64*32*16);
    };
    int DC = 49;
    if (needF(49) * sizeof(float) > ws_size) DC = 7;
    if (needF(7)  * sizeof(float) > ws_size) DC = 1;

    float* ws = (float*)d_ws;
    size_t off = 0;
    auto take = [&](size_t n) { float* p = ws + off; off += n; return p; };
    float* x0 = take((size_t)DC * 64 * 12288);
    float* x1 = take((size_t)DC * 96 * 12288);
    float* x2 = take((size_t)DC * 128 * 3072);
    float* x3 = take((size_t)DC * 128 * 3072);
    float* x4 = take((size_t)DC * 64 * 3072);
    float* x5 = take((size_t)DC * 32 * 12288);
    float* cost = take((size_t)49 * 12288);
    float* wr1[2], *wr2[2], *wr3[2], *wr4[2], *wr5[2];
    for (int l = 0; l < 2; ++l) {
        wr1[l] = take(96 * 64 * 9);
        wr2[l] = take(128 * 96 * 9);
        wr3[l] = take(128 * 128 * 9);
        wr4[l] = take(64 * 128 * 9);
        wr5[l] = take(64 * 32 * 16);
    }

    // repack all conv weights once per call
    for (int l = 0; l < 2; ++l) {
        k_repack_oihw<<<dim3(216), 256, 0, stream>>>(cw1 + (size_t)l * 96 * 64 * 9,  wr1[l], 96, 64);
        k_repack_oihw<<<dim3(432), 256, 0, stream>>>(cw2 + (size_t)l * 128 * 96 * 9, wr2[l], 128, 96);
        k_repack_oihw<<<dim3(576), 256, 0, stream>>>(cw3 + (size_t)l * 128 * 128 * 9, wr3[l], 128, 128);
        k_repack_oihw<<<dim3(288), 256, 0, stream>>>(cw4 + (size_t)l * 64 * 128 * 9, wr4[l], 64, 128);
        k_repack_ctw<<<dim3(128), 256, 0, stream>>>(ctw5 + (size_t)l * 64 * 32 * 16, wr5[l]);
    }

    for (int l = 0; l < 2; ++l) {
        const float inv_scale = l ? 0.5f : 1.0f;
        for (int d0 = 0; d0 < 49; d0 += DC) {
            k_sample_concat<<<dim3(48, 1, DC), 256, 0, stream>>>(
                fm1[l], fm2[l], coords, x0, d0, inv_scale);
            k_conv3x3_bn_relu<64, 96, 1, 96, 128, 96, 128>
                <<<dim3(48, 6, DC), 256, 0, stream>>>(x0, x1, wr1[l],
                    bn[0][0] + l * 96,  bn[0][1] + l * 96,  bn[0][2] + l * 96,  bn[0][3] + l * 96);
            k_conv3x3_bn_relu<96, 128, 2, 96, 128, 48, 64>
                <<<dim3(12, 8, DC), 256, 0, stream>>>(x1, x2, wr2[l],
                    bn[1][0] + l * 128, bn[1][1] + l * 128, bn[1][2] + l * 128, bn[1][3] + l * 128);
            k_conv3x3_bn_relu<128, 128, 1, 48, 64, 48, 64>
                <<<dim3(12, 8, DC), 256, 0, stream>>>(x2, x3, wr3[l],
                    bn[2][0] + l * 128, bn[2][1] + l * 128, bn[2][2] + l * 128, bn[2][3] + l * 128);
            k_conv3x3_bn_relu<128, 64, 1, 48, 64, 48, 64>
                <<<dim3(12, 4, DC), 256, 0, stream>>>(x3, x4, wr4[l],
                    bn[3][0] + l * 64,  bn[3][1] + l * 64,  bn[3][2] + l * 64,  bn[3][3] + l * 64);
            k_convt_bn_relu<<<dim3(12, 8, DC), 256, 0, stream>>>(x4, x5, wr5[l],
                    bn[4][0] + l * 32,  bn[4][1] + l * 32,  bn[4][2] + l * 32,  bn[4][3] + l * 32);
            k_conv6_bias<<<dim3(48, 1, DC), 256, 0, stream>>>(
                x5, cost, cw6 + (size_t)l * 32 * 9, cb6 + l, d0);
        }
        k_dap<<<dim3(48, 49), 256, 0, stream>>>(
            cost, dap + (size_t)l * 49 * 49, out + (size_t)l * 49 * 12288);
    }
}

// Round 2
// 1977.379 us; speedup vs baseline: 7.9473x; 7.9473x over previous
//
#include <hip/hip_runtime.h>

#define EPSF 1e-5f

typedef __attribute__((ext_vector_type(8))) short short8;
typedef __attribute__((ext_vector_type(4))) float f32x4;

__device__ __forceinline__ ushort f2bf(float x) {
    union { float f; unsigned u; } c; c.f = x;
    unsigned r = c.u + 0x7FFF + ((c.u >> 16) & 1);   // RNE
    return (ushort)(r >> 16);
}
__device__ __forceinline__ float bf2f(ushort b) {
    union { unsigned u; float f; } c; c.u = ((unsigned)b) << 16;
    return c.f;
}

// ---------------------------------------------------------------------------
// Geometry: B=1, C=32, H=96, W=128, L=2, N=7 (49 displacements)
// Activations: NHWC bf16  [dc][spatial][C]
// Weights:     [tap][COUT][CIN] bf16 (repacked per call)
// ---------------------------------------------------------------------------

// ---------------- weight repack: OIHW fp32 -> [9][CO][CI] bf16 -------------
__global__ __launch_bounds__(256) void k_repack_conv(
    const float* __restrict__ src, ushort* __restrict__ dst, int CO, int CI)
{
    int idx = blockIdx.x * 256 + threadIdx.x;
    if (idx >= CO * CI * 9) return;
    int co = idx / (CI * 9);
    int rem = idx % (CI * 9);
    int ci = rem / 9, tap = rem % 9;
    dst[((size_t)tap * CO + co) * CI + ci] = f2bf(src[idx]);
}

// ctw5 [64][32][4][4] fp32 -> [parity(4)][tab(4)][32][64] bf16
__global__ __launch_bounds__(256) void k_repack_ct(
    const float* __restrict__ src, ushort* __restrict__ dst)
{
    int idx = blockIdx.x * 256 + threadIdx.x;
    if (idx >= 4 * 4 * 32 * 64) return;
    int ci = idx & 63;
    int t = idx >> 6;
    int co = t & 31; t >>= 5;
    int tap = t & 3;
    int parity = t >> 2;
    int ph = parity >> 1, pw = parity & 1;
    int a = tap >> 1, b = tap & 1;
    int kh = ((ph + 1) & 1) + 2 * a;
    int kw = ((pw + 1) & 1) + 2 * b;
    dst[idx] = f2bf(src[((ci * 32 + co) * 4 + kh) * 4 + kw]);
}

// ---------------- sample + concat -> x0 NHWC bf16 [dc][12288][64] ----------
__global__ __launch_bounds__(256) void k_sample_nhwc(
    const float* __restrict__ f1, const float* __restrict__ f2,
    const float* __restrict__ coords, ushort* __restrict__ x0,
    int d0, float inv_scale)
{
    const int HW = 96 * 128;
    const int sp = blockIdx.x * 256 + threadIdx.x;
    const int dd = blockIdx.z;
    const int d = d0 + dd;
    const int du = d / 7, dv = d % 7;

    float cx = coords[sp] * inv_scale + (float)(du - 3);
    float cy = coords[HW + sp] * inv_scale + (float)(dv - 3);
    float xf = floorf(cx), yf = floorf(cy);
    float wx = cx - xf, wy = cy - yf;
    int xi = (int)xf, yi = (int)yf;
    float vx0 = (xf >= 0.f && xf <= 127.f) ? 1.f : 0.f;
    float vx1 = (xf + 1.f >= 0.f && xf + 1.f <= 127.f) ? 1.f : 0.f;
    float vy0 = (yf >= 0.f && yf <= 95.f) ? 1.f : 0.f;
    float vy1 = (yf + 1.f >= 0.f && yf + 1.f <= 95.f) ? 1.f : 0.f;
    int x0i = min(max(xi, 0), 127), x1i = min(max(xi + 1, 0), 127);
    int y0i = min(max(yi, 0), 95),  y1i = min(max(yi + 1, 0), 95);
    float w00 = (1.f - wx) * (1.f - wy) * vx0 * vy0;
    float w01 = wx * (1.f - wy) * vx1 * vy0;
    float w10 = (1.f - wx) * wy * vx0 * vy1;
    float w11 = wx * wy * vx1 * vy1;
    int o00 = y0i * 128 + x0i, o01 = y0i * 128 + x1i;
    int o10 = y1i * 128 + x0i, o11 = y1i * 128 + x1i;

    ushort* dst = x0 + ((size_t)dd * HW + sp) * 64;
    #pragma unroll
    for (int g = 0; g < 4; ++g) {               // f1 channels 0..31
        uint4 pk;
        uint* pw_ = (uint*)&pk;
        #pragma unroll
        for (int q = 0; q < 4; ++q) {
            int c = g * 8 + q * 2;
            pw_[q] = (uint)f2bf(f1[(size_t)c * HW + sp])
                   | ((uint)f2bf(f1[(size_t)(c + 1) * HW + sp]) << 16);
        }
        *(uint4*)(dst + g * 8) = pk;
    }
    #pragma unroll
    for (int g = 0; g < 4; ++g) {               // sampled f2 channels 32..63
        uint4 pk;
        uint* pw_ = (uint*)&pk;
        #pragma unroll
        for (int q = 0; q < 4; ++q) {
            uint wv = 0;
            #pragma unroll
            for (int h = 0; h < 2; ++h) {
                int c = g * 8 + q * 2 + h;
                const float* fc = f2 + (size_t)c * HW;
                float s = w00 * fc[o00] + w01 * fc[o01] + w10 * fc[o10] + w11 * fc[o11];
                wv |= ((uint)f2bf(s)) << (16 * h);
            }
            pw_[q] = wv;
        }
        *(uint4*)(dst + 32 + g * 8) = pk;
    }
}

// ---------------- MFMA conv3x3 (+BN+ReLU), NHWC bf16 -----------------------
// block = 256 thr (4 waves), wave tile = 32 m x COUT, block = 128 m
template <int CIN, int COUT, int STRIDE, int IH, int IW, int OH, int OW>
__global__ __launch_bounds__(256, 2) void k_conv_mfma(
    const ushort* __restrict__ in, ushort* __restrict__ out,
    const ushort* __restrict__ w,
    const float* __restrict__ bs, const float* __restrict__ bb,
    const float* __restrict__ bm, const float* __restrict__ bv)
{
    constexpr int NF = COUT / 16, CC = CIN / 32;
    constexpr int OHW = OH * OW, IHW = IH * IW;
    const int lane = threadIdx.x & 63, wid = threadIdx.x >> 6;
    const int m0 = blockIdx.x * 128 + wid * 32;
    const int d = blockIdx.z;
    const int lr = lane & 15, kg = lane >> 4;

    int ohm[2], owm[2];
    #pragma unroll
    for (int mf = 0; mf < 2; ++mf) {
        int m = m0 + mf * 16 + lr;
        ohm[mf] = m / OW; owm[mf] = m % OW;
    }

    const short8 z8 = {0, 0, 0, 0, 0, 0, 0, 0};
    f32x4 acc[2][NF];
    #pragma unroll
    for (int mf = 0; mf < 2; ++mf)
        #pragma unroll
        for (int nf = 0; nf < NF; ++nf)
            acc[mf][nf] = (f32x4){0.f, 0.f, 0.f, 0.f};

    const ushort* ib = in + (size_t)d * IHW * CIN;

    for (int kh = 0; kh < 3; ++kh) {
        for (int kw = 0; kw < 3; ++kw) {
            int srcoff[2]; bool val[2];
            #pragma unroll
            for (int mf = 0; mf < 2; ++mf) {
                int ih = ohm[mf] * STRIDE - 1 + kh;
                int iw = owm[mf] * STRIDE - 1 + kw;
                val[mf] = ((unsigned)ih < (unsigned)IH) && ((unsigned)iw < (unsigned)IW);
                int ihc = min(max(ih, 0), IH - 1);
                int iwc = min(max(iw, 0), IW - 1);
                srcoff[mf] = (ihc * IW + iwc) * CIN;
            }
            const ushort* wt = w + (size_t)(kh * 3 + kw) * COUT * CIN;
            #pragma unroll 1
            for (int cc = 0; cc < CC; ++cc) {
                const int kbase = cc * 32 + kg * 8;
                short8 a[2];
                #pragma unroll
                for (int mf = 0; mf < 2; ++mf) {
                    short8 v = *(const short8*)(ib + srcoff[mf] + kbase);
                    a[mf] = val[mf] ? v : z8;
                }
                #pragma unroll
                for (int nf = 0; nf < NF; ++nf) {
                    short8 bfr = *(const short8*)(wt + (size_t)(nf * 16 + lr) * CIN + kbase);
                    #pragma unroll
                    for (int mf = 0; mf < 2; ++mf)
                        acc[mf][nf] = __builtin_amdgcn_mfma_f32_16x16x32_bf16(
                            a[mf], bfr, acc[mf][nf], 0, 0, 0);
                }
            }
        }
    }

    ushort* ob = out + (size_t)d * OHW * COUT;
    #pragma unroll
    for (int nf = 0; nf < NF; ++nf) {
        const int col = nf * 16 + lr;
        const float inv = bs[col] * rsqrtf(bv[col] + EPSF);
        const float beta = bb[col] - bm[col] * inv;
        #pragma unroll
        for (int mf = 0; mf < 2; ++mf) {
            #pragma unroll
            for (int j = 0; j < 4; ++j) {
                int row = m0 + mf * 16 + kg * 4 + j;
                float y = fmaxf(fmaf(acc[mf][nf][j], inv, beta), 0.f);
                ob[(size_t)row * COUT + col] = f2bf(y);
            }
        }
    }
}

// ---------------- MFMA convT4x4 s2 (+BN+ReLU) ------------------------------
// in [dc][3072][64], out [dc][12288][32], w [parity][tap][32][64]
__global__ __launch_bounds__(256, 2) void k_convt_mfma(
    const ushort* __restrict__ in, ushort* __restrict__ out,
    const ushort* __restrict__ w,
    const float* __restrict__ bs, const float* __restrict__ bb,
    const float* __restrict__ bm, const float* __restrict__ bv)
{
    const int lane = threadIdx.x & 63, wid = threadIdx.x >> 6;
    const int m0 = blockIdx.x * 128 + wid * 32;
    const int parity = blockIdx.y;
    const int d = blockIdx.z;
    const int ph = parity >> 1, pw = parity & 1;
    const int kh0 = (ph + 1) & 1, kw0 = (pw + 1) & 1;
    const int lr = lane & 15, kg = lane >> 4;

    int ihA[2], iwA[2];
    #pragma unroll
    for (int mf = 0; mf < 2; ++mf) {
        int m = m0 + mf * 16 + lr;
        int q = m >> 6, r = m & 63;
        ihA[mf] = (2 * q + ph + 1 - kh0) >> 1;
        iwA[mf] = (2 * r + pw + 1 - kw0) >> 1;
    }

    const short8 z8 = {0, 0, 0, 0, 0, 0, 0, 0};
    f32x4 acc[2][2];
    #pragma unroll
    for (int mf = 0; mf < 2; ++mf)
        #pragma unroll
        for (int nf = 0; nf < 2; ++nf)
            acc[mf][nf] = (f32x4){0.f, 0.f, 0.f, 0.f};

    const ushort* ib = in + (size_t)d * 3072 * 64;

    #pragma unroll
    for (int a = 0; a < 2; ++a) {
        #pragma unroll
        for (int b = 0; b < 2; ++b) {
            int srcoff[2]; bool val[2];
            #pragma unroll
            for (int mf = 0; mf < 2; ++mf) {
                int ih = ihA[mf] - a;
                int iw = iwA[mf] - b;
                val[mf] = ((unsigned)ih < 48u) && ((unsigned)iw < 64u);
                int ihc = min(max(ih, 0), 47), iwc = min(max(iw, 0), 63);
                srcoff[mf] = (ihc * 64 + iwc) * 64;
            }
            const ushort* wt = w + (size_t)((parity * 4 + a * 2 + b) * 32) * 64;
            #pragma unroll 1
            for (int cc = 0; cc < 2; ++cc) {
                const int kbase = cc * 32 + kg * 8;
                short8 av[2];
                #pragma unroll
                for (int mf = 0; mf < 2; ++mf) {
                    short8 v = *(const short8*)(ib + srcoff[mf] + kbase);
                    av[mf] = val[mf] ? v : z8;
                }
                #pragma unroll
                for (int nf = 0; nf < 2; ++nf) {
                    short8 bfr = *(const short8*)(wt + (size_t)(nf * 16 + lr) * 64 + kbase);
                    #pragma unroll
                    for (int mf = 0; mf < 2; ++mf)
                        acc[mf][nf] = __builtin_amdgcn_mfma_f32_16x16x32_bf16(
                            av[mf], bfr, acc[mf][nf], 0, 0, 0);
                }
            }
        }
    }

    ushort* ob = out + (size_t)d * 12288 * 32;
    #pragma unroll
    for (int nf = 0; nf < 2; ++nf) {
        const int col = nf * 16 + lr;
        const float inv = bs[col] * rsqrtf(bv[col] + EPSF);
        const float beta = bb[col] - bm[col] * inv;
        #pragma unroll
        for (int mf = 0; mf < 2; ++mf) {
            #pragma unroll
            for (int j = 0; j < 4; ++j) {
                int m = m0 + mf * 16 + kg * 4 + j;
                int q = m >> 6, r = m & 63;
                int sp = (2 * q + ph) * 128 + (2 * r + pw);
                float y = fmaxf(fmaf(acc[mf][nf][j], inv, beta), 0.f);
                ob[(size_t)sp * 32 + col] = f2bf(y);
            }
        }
    }
}

// ---------------- conv6 (32->1) + bias, NHWC bf16 in, fp32 out -------------
__global__ __launch_bounds__(256) void k_conv6(
    const ushort* __restrict__ x5,    // [dc][12288][32]
    float* __restrict__ cost,         // [49][12288]
    const float* __restrict__ w,      // [32][3][3]
    const float* __restrict__ biasp, int d0)
{
    const int sp = blockIdx.x * 256 + threadIdx.x;
    const int dd = blockIdx.z;
    const int oh = sp >> 7, ow = sp & 127;
    float acc = 0.f;
    #pragma unroll
    for (int kh = 0; kh < 3; ++kh) {
        const int ih = oh - 1 + kh;
        if (ih < 0 || ih >= 96) continue;
        #pragma unroll
        for (int kw = 0; kw < 3; ++kw) {
            const int iw = ow - 1 + kw;
            if (iw < 0 || iw >= 128) continue;
            const ushort* p = x5 + ((size_t)dd * 12288 + ih * 128 + iw) * 32;
            const int tap = kh * 3 + kw;
            #pragma unroll
            for (int q = 0; q < 4; ++q) {
                uint4 v = *(const uint4*)(p + q * 8);
                const uint* vw = (const uint*)&v;
                #pragma unroll
                for (int t = 0; t < 4; ++t) {
                    int ci = q * 8 + t * 2;
                    acc = fmaf(bf2f((ushort)(vw[t] & 0xFFFF)), w[ci * 9 + tap], acc);
                    acc = fmaf(bf2f((ushort)(vw[t] >> 16)), w[(ci + 1) * 9 + tap], acc);
                }
            }
        }
    }
    cost[(size_t)(d0 + dd) * 12288 + sp] = acc + biasp[0];
}

// ---------------- DAP ------------------------------------------------------
__global__ __launch_bounds__(256) void k_dap(
    const float* __restrict__ cost, const float* __restrict__ dw,
    float* __restrict__ out)
{
    const int sp = blockIdx.x * 256 + threadIdx.x;
    const int p = blockIdx.y;
    const float* dr = dw + p * 49;
    float acc = 0.f;
    #pragma unroll
    for (int q = 0; q < 49; ++q)
        acc = fmaf(dr[q], cost[(size_t)q * 12288 + sp], acc);
    out[(size_t)p * 12288 + sp] = acc;
}

// ---------------------------------------------------------------------------
extern "C" void kernel_launch(void* const* d_in, const int* in_sizes, int n_in,
                              void* d_out, int out_size, void* d_ws, size_t ws_size,
                              hipStream_t stream)
{
    const float* fm1[2] = { (const float*)d_in[0], (const float*)d_in[2] };
    const float* fm2[2] = { (const float*)d_in[1], (const float*)d_in[3] };
    const float* coords = (const float*)d_in[4];
    const float* cw1  = (const float*)d_in[5];
    const float* cw2  = (const float*)d_in[6];
    const float* cw3  = (const float*)d_in[7];
    const float* cw4  = (const float*)d_in[8];
    const float* ctw5 = (const float*)d_in[9];
    const float* cw6  = (const float*)d_in[10];
    const float* cb6  = (const float*)d_in[11];
    const float* bn[5][4];
    for (int j = 0; j < 5; ++j)
        for (int k = 0; k < 4; ++k)
            bn[j][k] = (const float*)d_in[12 + j * 4 + k];
    const float* dap = (const float*)d_in[32];
    float* out = (float*)d_out;

    // ---- workspace layout (bytes): bufA | bufB | weights | cost ----
    const size_t A_US = 786432;   // per-d ushorts: max(x0 64ch@12288, x2 128ch@3072, x4)
    const size_t B_US = 1179648;  // per-d ushorts: max(x1 96ch@12288, x3, x5)
    const size_t W_US = 2 * (9*96*64 + 9*128*96 + 9*128*128 + 9*64*128 + 16*32*64);
    const size_t COST_B = 49 * 12288 * sizeof(float);

    int DC = 1;
    for (int cand : {49, 33, 25, 17, 13, 9, 7, 5, 3, 2, 1}) {
        size_t need = (A_US + B_US) * (size_t)cand * 2 + W_US * 2 + COST_B + 256;
        if (need <= ws_size) { DC = cand; break; }
    }

    char* wsb = (char*)d_ws;
    ushort* bufA = (ushort*)wsb;
    ushort* bufB = bufA + A_US * DC;
    ushort* wp = bufB + B_US * DC;
    ushort* wr1[2], *wr2[2], *wr3[2], *wr4[2], *wr5[2];
    for (int l = 0; l < 2; ++l) {
        wr1[l] = wp; wp += 9 * 96 * 64;
        wr2[l] = wp; wp += 9 * 128 * 96;
        wr3[l] = wp; wp += 9 * 128 * 128;
        wr4[l] = wp; wp += 9 * 64 * 128;
        wr5[l] = wp; wp += 16 * 32 * 64;
    }
    float* cost = (float*)wp;

    // ---- repack weights (once per call) ----
    for (int l = 0; l < 2; ++l) {
        k_repack_conv<<<dim3(216), 256, 0, stream>>>(cw1 + (size_t)l * 96 * 64 * 9,   wr1[l], 96, 64);
        k_repack_conv<<<dim3(432), 256, 0, stream>>>(cw2 + (size_t)l * 128 * 96 * 9,  wr2[l], 128, 96);
        k_repack_conv<<<dim3(576), 256, 0, stream>>>(cw3 + (size_t)l * 128 * 128 * 9, wr3[l], 128, 128);
        k_repack_conv<<<dim3(288), 256, 0, stream>>>(cw4 + (size_t)l * 64 * 128 * 9,  wr4[l], 64, 128);
        k_repack_ct<<<dim3(128), 256, 0, stream>>>(ctw5 + (size_t)l * 64 * 32 * 16, wr5[l]);
    }

    for (int l = 0; l < 2; ++l) {
        const float inv_scale = l ? 0.5f : 1.0f;
        for (int d0 = 0; d0 < 49; d0 += DC) {
            const int dc = min(DC, 49 - d0);
            k_sample_nhwc<<<dim3(48, 1, dc), 256, 0, stream>>>(
                fm1[l], fm2[l], coords, bufA, d0, inv_scale);
            k_conv_mfma<64, 96, 1, 96, 128, 96, 128>
                <<<dim3(96, 1, dc), 256, 0, stream>>>(bufA, bufB, wr1[l],
                    bn[0][0] + l * 96,  bn[0][1] + l * 96,  bn[0][2] + l * 96,  bn[0][3] + l * 96);
            k_conv_mfma<96, 128, 2, 96, 128, 48, 64>
                <<<dim3(24, 1, dc), 256, 0, stream>>>(bufB, bufA, wr2[l],
                    bn[1][0] + l * 128, bn[1][1] + l * 128, bn[1][2] + l * 128, bn[1][3] + l * 128);
            k_conv_mfma<128, 128, 1, 48, 64, 48, 64>
                <<<dim3(24, 1, dc), 256, 0, stream>>>(bufA, bufB, wr3[l],
                    bn[2][0] + l * 128, bn[2][1] + l * 128, bn[2][2] + l * 128, bn[2][3] + l * 128);
            k_conv_mfma<128, 64, 1, 48, 64, 48, 64>
                <<<dim3(24, 1, dc), 256, 0, stream>>>(bufB, bufA, wr4[l],
                    bn[3][0] + l * 64,  bn[3][1] + l * 64,  bn[3][2] + l * 64,  bn[3][3] + l * 64);
            k_convt_mfma<<<dim3(24, 4, dc), 256, 0, stream>>>(bufA, bufB, wr5[l],
                    bn[4][0] + l * 32,  bn[4][1] + l * 32,  bn[4][2] + l * 32,  bn[4][3] + l * 32);
            k_conv6<<<dim3(48, 1, dc), 256, 0, stream>>>(
                bufB, cost, cw6 + (size_t)l * 32 * 9, cb6 + l, d0);
        }
        k_dap<<<dim3(48, 49), 256, 0, stream>>>(
            cost, dap + (size_t)l * 49 * 49, out + (size_t)l * 49 * 12288);
    }
}

// Round 3
// 1499.123 us; speedup vs baseline: 10.4826x; 1.3190x over previous
//
#include <hip/hip_runtime.h>

#define EPSF 1e-5f

typedef __attribute__((ext_vector_type(8))) short short8;
typedef __attribute__((ext_vector_type(4))) float f32x4;

__device__ __forceinline__ ushort f2bf(float x) {
    union { float f; unsigned u; } c; c.f = x;
    unsigned r = c.u + 0x7FFF + ((c.u >> 16) & 1);   // RNE
    return (ushort)(r >> 16);
}
__device__ __forceinline__ float bf2f(ushort b) {
    union { unsigned u; float f; } c; c.u = ((unsigned)b) << 16;
    return c.f;
}

// ---------------------------------------------------------------------------
// Geometry: B=1, C=32, H=96, W=128, L=2, N=7 (49 displacements)
// Activations: NHWC bf16  [dc][spatial][C]
// Weights:     [tap][COUT][CIN] bf16 (repacked per call)
// ---------------------------------------------------------------------------

// ---------------- weight repack: OIHW fp32 -> [9][CO][CI] bf16 -------------
__global__ __launch_bounds__(256) void k_repack_conv(
    const float* __restrict__ src, ushort* __restrict__ dst, int CO, int CI)
{
    int idx = blockIdx.x * 256 + threadIdx.x;
    if (idx >= CO * CI * 9) return;
    int co = idx / (CI * 9);
    int rem = idx % (CI * 9);
    int ci = rem / 9, tap = rem % 9;
    dst[((size_t)tap * CO + co) * CI + ci] = f2bf(src[idx]);
}

// ctw5 [64][32][4][4] fp32 -> [parity(4)][tap(4)][32][64] bf16
__global__ __launch_bounds__(256) void k_repack_ct(
    const float* __restrict__ src, ushort* __restrict__ dst)
{
    int idx = blockIdx.x * 256 + threadIdx.x;
    if (idx >= 4 * 4 * 32 * 64) return;
    int ci = idx & 63;
    int t = idx >> 6;
    int co = t & 31; t >>= 5;
    int tap = t & 3;
    int parity = t >> 2;
    int ph = parity >> 1, pw = parity & 1;
    int a = tap >> 1, b = tap & 1;
    int kh = ((ph + 1) & 1) + 2 * a;
    int kw = ((pw + 1) & 1) + 2 * b;
    dst[idx] = f2bf(src[((ci * 32 + co) * 4 + kh) * 4 + kw]);
}

// ---------------- sample + concat -> x0 NHWC bf16 [dc][12288][64] ----------
__global__ __launch_bounds__(256) void k_sample_nhwc(
    const float* __restrict__ f1, const float* __restrict__ f2,
    const float* __restrict__ coords, ushort* __restrict__ x0,
    int d0, float inv_scale)
{
    const int HW = 96 * 128;
    const int sp = blockIdx.x * 256 + threadIdx.x;
    const int dd = blockIdx.z;
    const int d = d0 + dd;
    const int du = d / 7, dv = d % 7;

    float cx = coords[sp] * inv_scale + (float)(du - 3);
    float cy = coords[HW + sp] * inv_scale + (float)(dv - 3);
    float xf = floorf(cx), yf = floorf(cy);
    float wx = cx - xf, wy = cy - yf;
    int xi = (int)xf, yi = (int)yf;
    float vx0 = (xf >= 0.f && xf <= 127.f) ? 1.f : 0.f;
    float vx1 = (xf + 1.f >= 0.f && xf + 1.f <= 127.f) ? 1.f : 0.f;
    float vy0 = (yf >= 0.f && yf <= 95.f) ? 1.f : 0.f;
    float vy1 = (yf + 1.f >= 0.f && yf + 1.f <= 95.f) ? 1.f : 0.f;
    int x0i = min(max(xi, 0), 127), x1i = min(max(xi + 1, 0), 127);
    int y0i = min(max(yi, 0), 95),  y1i = min(max(yi + 1, 0), 95);
    float w00 = (1.f - wx) * (1.f - wy) * vx0 * vy0;
    float w01 = wx * (1.f - wy) * vx1 * vy0;
    float w10 = (1.f - wx) * wy * vx0 * vy1;
    float w11 = wx * wy * vx1 * vy1;
    int o00 = y0i * 128 + x0i, o01 = y0i * 128 + x1i;
    int o10 = y1i * 128 + x0i, o11 = y1i * 128 + x1i;

    ushort* dst = x0 + ((size_t)dd * HW + sp) * 64;
    #pragma unroll
    for (int g = 0; g < 4; ++g) {               // f1 channels 0..31
        uint4 pk;
        uint* pw_ = (uint*)&pk;
        #pragma unroll
        for (int q = 0; q < 4; ++q) {
            int c = g * 8 + q * 2;
            pw_[q] = (uint)f2bf(f1[(size_t)c * HW + sp])
                   | ((uint)f2bf(f1[(size_t)(c + 1) * HW + sp]) << 16);
        }
        *(uint4*)(dst + g * 8) = pk;
    }
    #pragma unroll
    for (int g = 0; g < 4; ++g) {               // sampled f2 channels 32..63
        uint4 pk;
        uint* pw_ = (uint*)&pk;
        #pragma unroll
        for (int q = 0; q < 4; ++q) {
            uint wv = 0;
            #pragma unroll
            for (int h = 0; h < 2; ++h) {
                int c = g * 8 + q * 2 + h;
                const float* fc = f2 + (size_t)c * HW;
                float s = w00 * fc[o00] + w01 * fc[o01] + w10 * fc[o10] + w11 * fc[o11];
                wv |= ((uint)f2bf(s)) << (16 * h);
            }
            pw_[q] = wv;
        }
        *(uint4*)(dst + 32 + g * 8) = pk;
    }
}

// ---------------- MFMA conv3x3 (+BN+ReLU), NHWC bf16 -----------------------
// block = 256 thr (4 waves), wave tile = 64 m x COUT, block = 256 m
template <int CIN, int COUT, int STRIDE, int IH, int IW, int OH, int OW>
__global__ __launch_bounds__(256) void k_conv_mfma(
    const ushort* __restrict__ in, ushort* __restrict__ out,
    const ushort* __restrict__ w,
    const float* __restrict__ bs, const float* __restrict__ bb,
    const float* __restrict__ bm, const float* __restrict__ bv)
{
    constexpr int NF = COUT / 16, CC = CIN / 32, MF = 4;
    constexpr int OHW = OH * OW, IHW = IH * IW;
    constexpr int OWS = (OW == 128) ? 7 : 6;
    const int lane = threadIdx.x & 63, wid = threadIdx.x >> 6;
    const int m0 = blockIdx.x * 256 + wid * 64;
    const int d = blockIdx.z;
    const int lr = lane & 15, kg = lane >> 4;

    int bh[MF], bw[MF];
    #pragma unroll
    for (int mf = 0; mf < MF; ++mf) {
        int m = m0 + mf * 16 + lr;
        bh[mf] = (m >> OWS) * STRIDE - 1;
        bw[mf] = (m & (OW - 1)) * STRIDE - 1;
    }

    const short8 z8 = {0, 0, 0, 0, 0, 0, 0, 0};
    f32x4 acc[MF][NF];
    #pragma unroll
    for (int mf = 0; mf < MF; ++mf)
        #pragma unroll
        for (int nf = 0; nf < NF; ++nf)
            acc[mf][nf] = (f32x4){0.f, 0.f, 0.f, 0.f};

    const ushort* ib = in + (size_t)d * IHW * CIN;

    for (int kh = 0; kh < 3; ++kh) {
        for (int kw = 0; kw < 3; ++kw) {
            int srcoff[MF]; bool val[MF];
            #pragma unroll
            for (int mf = 0; mf < MF; ++mf) {
                int ih = bh[mf] + kh;
                int iw = bw[mf] + kw;
                val[mf] = ((unsigned)ih < (unsigned)IH) && ((unsigned)iw < (unsigned)IW);
                int ihc = min(max(ih, 0), IH - 1);
                int iwc = min(max(iw, 0), IW - 1);
                srcoff[mf] = (ihc * IW + iwc) * CIN;
            }
            const ushort* wt = w + (size_t)(kh * 3 + kw) * COUT * CIN;
            #pragma unroll
            for (int cc = 0; cc < CC; ++cc) {
                const int kbase = cc * 32 + kg * 8;
                short8 a[MF];
                #pragma unroll
                for (int mf = 0; mf < MF; ++mf) {
                    short8 v = *(const short8*)(ib + srcoff[mf] + kbase);
                    a[mf] = val[mf] ? v : z8;
                }
                #pragma unroll
                for (int nf = 0; nf < NF; ++nf) {
                    short8 bfr = *(const short8*)(wt + (size_t)(nf * 16 + lr) * CIN + kbase);
                    #pragma unroll
                    for (int mf = 0; mf < MF; ++mf)
                        acc[mf][nf] = __builtin_amdgcn_mfma_f32_16x16x32_bf16(
                            a[mf], bfr, acc[mf][nf], 0, 0, 0);
                }
            }
        }
    }

    ushort* ob = out + (size_t)d * OHW * COUT;
    #pragma unroll
    for (int nf = 0; nf < NF; ++nf) {
        const int col = nf * 16 + lr;
        const float inv = bs[col] * rsqrtf(bv[col] + EPSF);
        const float beta = bb[col] - bm[col] * inv;
        #pragma unroll
        for (int mf = 0; mf < MF; ++mf) {
            #pragma unroll
            for (int j = 0; j < 4; ++j) {
                int row = m0 + mf * 16 + kg * 4 + j;
                float y = fmaxf(fmaf(acc[mf][nf][j], inv, beta), 0.f);
                ob[(size_t)row * COUT + col] = f2bf(y);
            }
        }
    }
}

// ---------------- MFMA convT4x4 s2 (+BN+ReLU) ------------------------------
// in [dc][3072][64], out [dc][12288][32], w [parity][tap][32][64]
__global__ __launch_bounds__(256) void k_convt_mfma(
    const ushort* __restrict__ in, ushort* __restrict__ out,
    const ushort* __restrict__ w,
    const float* __restrict__ bs, const float* __restrict__ bb,
    const float* __restrict__ bm, const float* __restrict__ bv)
{
    constexpr int MF = 4;
    const int lane = threadIdx.x & 63, wid = threadIdx.x >> 6;
    const int m0 = blockIdx.x * 256 + wid * 64;
    const int parity = blockIdx.y;
    const int d = blockIdx.z;
    const int ph = parity >> 1, pw = parity & 1;
    const int kh0 = (ph + 1) & 1, kw0 = (pw + 1) & 1;
    const int lr = lane & 15, kg = lane >> 4;

    int ihA[MF], iwA[MF];
    #pragma unroll
    for (int mf = 0; mf < MF; ++mf) {
        int m = m0 + mf * 16 + lr;
        int q = m >> 6, r = m & 63;
        ihA[mf] = (2 * q + ph + 1 - kh0) >> 1;
        iwA[mf] = (2 * r + pw + 1 - kw0) >> 1;
    }

    const short8 z8 = {0, 0, 0, 0, 0, 0, 0, 0};
    f32x4 acc[MF][2];
    #pragma unroll
    for (int mf = 0; mf < MF; ++mf)
        #pragma unroll
        for (int nf = 0; nf < 2; ++nf)
            acc[mf][nf] = (f32x4){0.f, 0.f, 0.f, 0.f};

    const ushort* ib = in + (size_t)d * 3072 * 64;

    #pragma unroll
    for (int a = 0; a < 2; ++a) {
        #pragma unroll
        for (int b = 0; b < 2; ++b) {
            int srcoff[MF]; bool val[MF];
            #pragma unroll
            for (int mf = 0; mf < MF; ++mf) {
                int ih = ihA[mf] - a;
                int iw = iwA[mf] - b;
                val[mf] = ((unsigned)ih < 48u) && ((unsigned)iw < 64u);
                int ihc = min(max(ih, 0), 47), iwc = min(max(iw, 0), 63);
                srcoff[mf] = (ihc * 64 + iwc) * 64;
            }
            const ushort* wt = w + (size_t)((parity * 4 + a * 2 + b) * 32) * 64;
            #pragma unroll
            for (int cc = 0; cc < 2; ++cc) {
                const int kbase = cc * 32 + kg * 8;
                short8 av[MF];
                #pragma unroll
                for (int mf = 0; mf < MF; ++mf) {
                    short8 v = *(const short8*)(ib + srcoff[mf] + kbase);
                    av[mf] = val[mf] ? v : z8;
                }
                #pragma unroll
                for (int nf = 0; nf < 2; ++nf) {
                    short8 bfr = *(const short8*)(wt + (size_t)(nf * 16 + lr) * 64 + kbase);
                    #pragma unroll
                    for (int mf = 0; mf < MF; ++mf)
                        acc[mf][nf] = __builtin_amdgcn_mfma_f32_16x16x32_bf16(
                            av[mf], bfr, acc[mf][nf], 0, 0, 0);
                }
            }
        }
    }

    ushort* ob = out + (size_t)d * 12288 * 32;
    #pragma unroll
    for (int nf = 0; nf < 2; ++nf) {
        const int col = nf * 16 + lr;
        const float inv = bs[col] * rsqrtf(bv[col] + EPSF);
        const float beta = bb[col] - bm[col] * inv;
        #pragma unroll
        for (int mf = 0; mf < MF; ++mf) {
            #pragma unroll
            for (int j = 0; j < 4; ++j) {
                int m = m0 + mf * 16 + kg * 4 + j;
                int q = m >> 6, r = m & 63;
                int sp = (2 * q + ph) * 128 + (2 * r + pw);
                float y = fmaxf(fmaf(acc[mf][nf][j], inv, beta), 0.f);
                ob[(size_t)sp * 32 + col] = f2bf(y);
            }
        }
    }
}

// ---------------- conv6 (32->1) + bias, NHWC bf16 in, fp32 out -------------
__global__ __launch_bounds__(256) void k_conv6(
    const ushort* __restrict__ x5,    // [dc][12288][32]
    float* __restrict__ cost,         // [49][12288]
    const float* __restrict__ w,      // [32][3][3]
    const float* __restrict__ biasp, int d0)
{
    const int sp = blockIdx.x * 256 + threadIdx.x;
    const int dd = blockIdx.z;
    const int oh = sp >> 7, ow = sp & 127;
    float acc = 0.f;
    #pragma unroll
    for (int kh = 0; kh < 3; ++kh) {
        const int ih = oh - 1 + kh;
        if (ih < 0 || ih >= 96) continue;
        #pragma unroll
        for (int kw = 0; kw < 3; ++kw) {
            const int iw = ow - 1 + kw;
            if (iw < 0 || iw >= 128) continue;
            const ushort* p = x5 + ((size_t)dd * 12288 + ih * 128 + iw) * 32;
            const int tap = kh * 3 + kw;
            #pragma unroll
            for (int q = 0; q < 4; ++q) {
                uint4 v = *(const uint4*)(p + q * 8);
                const uint* vw = (const uint*)&v;
                #pragma unroll
                for (int t = 0; t < 4; ++t) {
                    int ci = q * 8 + t * 2;
                    acc = fmaf(bf2f((ushort)(vw[t] & 0xFFFF)), w[ci * 9 + tap], acc);
                    acc = fmaf(bf2f((ushort)(vw[t] >> 16)), w[(ci + 1) * 9 + tap], acc);
                }
            }
        }
    }
    cost[(size_t)(d0 + dd) * 12288 + sp] = acc + biasp[0];
}

// ---------------- DAP ------------------------------------------------------
__global__ __launch_bounds__(256) void k_dap(
    const float* __restrict__ cost, const float* __restrict__ dw,
    float* __restrict__ out)
{
    const int sp = blockIdx.x * 256 + threadIdx.x;
    const int p = blockIdx.y;
    const float* dr = dw + p * 49;
    float acc = 0.f;
    #pragma unroll
    for (int q = 0; q < 49; ++q)
        acc = fmaf(dr[q], cost[(size_t)q * 12288 + sp], acc);
    out[(size_t)p * 12288 + sp] = acc;
}

// ---------------------------------------------------------------------------
extern "C" void kernel_launch(void* const* d_in, const int* in_sizes, int n_in,
                              void* d_out, int out_size, void* d_ws, size_t ws_size,
                              hipStream_t stream)
{
    const float* fm1[2] = { (const float*)d_in[0], (const float*)d_in[2] };
    const float* fm2[2] = { (const float*)d_in[1], (const float*)d_in[3] };
    const float* coords = (const float*)d_in[4];
    const float* cw1  = (const float*)d_in[5];
    const float* cw2  = (const float*)d_in[6];
    const float* cw3  = (const float*)d_in[7];
    const float* cw4  = (const float*)d_in[8];
    const float* ctw5 = (const float*)d_in[9];
    const float* cw6  = (const float*)d_in[10];
    const float* cb6  = (const float*)d_in[11];
    const float* bn[5][4];
    for (int j = 0; j < 5; ++j)
        for (int k = 0; k < 4; ++k)
            bn[j][k] = (const float*)d_in[12 + j * 4 + k];
    const float* dap = (const float*)d_in[32];
    float* out = (float*)d_out;

    // ---- workspace layout (bytes): bufA | bufB | weights | cost ----
    const size_t A_US = 786432;   // per-d ushorts: max(x0 64ch@12288, x2 128ch@3072, x4)
    const size_t B_US = 1179648;  // per-d ushorts: max(x1 96ch@12288, x3, x5)
    const size_t W_US = 2 * (9*96*64 + 9*128*96 + 9*128*128 + 9*64*128 + 16*32*64);
    const size_t COST_B = 49 * 12288 * sizeof(float);

    int DC = 1;
    for (int cand : {49, 33, 25, 17, 13, 9, 7, 5, 3, 2, 1}) {
        size_t need = (A_US + B_US) * (size_t)cand * 2 + W_US * 2 + COST_B + 256;
        if (need <= ws_size) { DC = cand; break; }
    }

    char* wsb = (char*)d_ws;
    ushort* bufA = (ushort*)wsb;
    ushort* bufB = bufA + A_US * DC;
    ushort* wp = bufB + B_US * DC;
    ushort* wr1[2], *wr2[2], *wr3[2], *wr4[2], *wr5[2];
    for (int l = 0; l < 2; ++l) {
        wr1[l] = wp; wp += 9 * 96 * 64;
        wr2[l] = wp; wp += 9 * 128 * 96;
        wr3[l] = wp; wp += 9 * 128 * 128;
        wr4[l] = wp; wp += 9 * 64 * 128;
        wr5[l] = wp; wp += 16 * 32 * 64;
    }
    float* cost = (float*)wp;

    // ---- repack weights (once per call) ----
    for (int l = 0; l < 2; ++l) {
        k_repack_conv<<<dim3(216), 256, 0, stream>>>(cw1 + (size_t)l * 96 * 64 * 9,   wr1[l], 96, 64);
        k_repack_conv<<<dim3(432), 256, 0, stream>>>(cw2 + (size_t)l * 128 * 96 * 9,  wr2[l], 128, 96);
        k_repack_conv<<<dim3(576), 256, 0, stream>>>(cw3 + (size_t)l * 128 * 128 * 9, wr3[l], 128, 128);
        k_repack_conv<<<dim3(288), 256, 0, stream>>>(cw4 + (size_t)l * 64 * 128 * 9,  wr4[l], 64, 128);
        k_repack_ct<<<dim3(128), 256, 0, stream>>>(ctw5 + (size_t)l * 64 * 32 * 16, wr5[l]);
    }

    for (int l = 0; l < 2; ++l) {
        const float inv_scale = l ? 0.5f : 1.0f;
        for (int d0 = 0; d0 < 49; d0 += DC) {
            const int dc = min(DC, 49 - d0);
            k_sample_nhwc<<<dim3(48, 1, dc), 256, 0, stream>>>(
                fm1[l], fm2[l], coords, bufA, d0, inv_scale);
            k_conv_mfma<64, 96, 1, 96, 128, 96, 128>
                <<<dim3(48, 1, dc), 256, 0, stream>>>(bufA, bufB, wr1[l],
                    bn[0][0] + l * 96,  bn[0][1] + l * 96,  bn[0][2] + l * 96,  bn[0][3] + l * 96);
            k_conv_mfma<96, 128, 2, 96, 128, 48, 64>
                <<<dim3(12, 1, dc), 256, 0, stream>>>(bufB, bufA, wr2[l],
                    bn[1][0] + l * 128, bn[1][1] + l * 128, bn[1][2] + l * 128, bn[1][3] + l * 128);
            k_conv_mfma<128, 128, 1, 48, 64, 48, 64>
                <<<dim3(12, 1, dc), 256, 0, stream>>>(bufA, bufB, wr3[l],
                    bn[2][0] + l * 128, bn[2][1] + l * 128, bn[2][2] + l * 128, bn[2][3] + l * 128);
            k_conv_mfma<128, 64, 1, 48, 64, 48, 64>
                <<<dim3(12, 1, dc), 256, 0, stream>>>(bufB, bufA, wr4[l],
                    bn[3][0] + l * 64,  bn[3][1] + l * 64,  bn[3][2] + l * 64,  bn[3][3] + l * 64);
            k_convt_mfma<<<dim3(12, 4, dc), 256, 0, stream>>>(bufA, bufB, wr5[l],
                    bn[4][0] + l * 32,  bn[4][1] + l * 32,  bn[4][2] + l * 32,  bn[4][3] + l * 32);
            k_conv6<<<dim3(48, 1, dc), 256, 0, stream>>>(
                bufB, cost, cw6 + (size_t)l * 32 * 9, cb6 + l, d0);
        }
        k_dap<<<dim3(48, 49), 256, 0, stream>>>(
            cost, dap + (size_t)l * 49 * 49, out + (size_t)l * 49 * 12288);
    }
}